// Round 10
// baseline (565.896 us; speedup 1.0000x reference)
//
#include <hip/hip_runtime.h>
#include <hip/hip_bf16.h>
#include <math.h>

#define NEGINF (-INFINITY)

typedef float f32x4 __attribute__((ext_vector_type(4)));

__device__ __forceinline__ float wave_max_f(float m) {
#pragma unroll
  for (int d = 32; d > 0; d >>= 1) m = fmaxf(m, __shfl_xor(m, d, 64));
  return m;
}
__device__ __forceinline__ float wave_sum_f(float s) {
#pragma unroll
  for (int d = 32; d > 0; d >>= 1) s += __shfl_xor(s, d, 64);
  return s;
}
__device__ __forceinline__ int wave_sum_i(int s) {
#pragma unroll
  for (int d = 32; d > 0; d >>= 1) s += __shfl_xor(s, d, 64);
  return s;
}

// Whole-wave shift-right-by-1 via DPP (pure VALU). Lane l gets lane l-1's
// value; lane 0 gets 0 (caller overrides).
__device__ __forceinline__ float dpp_wave_shr1(float x) {
  int r = __builtin_amdgcn_mov_dpp(__float_as_int(x), 0x138, 0xf, 0xf, true);
  return __int_as_float(r);
}

// ---------------------------------------------------------------------------
// Kernel A: per (b,t) row of ctc_out[V]: logsumexp, then gather into packed
// row layout (stride ROWF=LANES*4+8 floats = 960 B):
//   row[0 .. LANES*4)  = label lps, quad s -> labels jbase(s)..+3 (clamped)
//   row[LANES*4]       = blank lp   (i.e. lane 58's quad .x = blank)
//   row[LANES*4+1 ..]  = zero pad
// ---------------------------------------------------------------------------
__global__ __launch_bounds__(256) void kA_lse_gather(
    const float* __restrict__ ctc_out, const int* __restrict__ ctc_label,
    float* __restrict__ lp, int B, int T, int V, int L, int LANES,
    int TPAD, int ROWF)
{
  extern __shared__ float shrow[];  // V floats
  __shared__ float wred[4];
  int row = blockIdx.x;             // b*T + t
  int b = row / T;
  int t = row - b * T;
  int tid = threadIdx.x;
  int w = tid >> 6;
  const float* x = ctc_out + (size_t)row * V;

  float m = NEGINF;
  int nf4 = V >> 2;
  for (int k = tid; k < nf4; k += 256) {
    float4 v = reinterpret_cast<const float4*>(x)[k];
    reinterpret_cast<float4*>(shrow)[k] = v;
    m = fmaxf(m, fmaxf(fmaxf(v.x, v.y), fmaxf(v.z, v.w)));
  }
  for (int k = (nf4 << 2) + tid; k < V; k += 256) {
    float v = x[k]; shrow[k] = v; m = fmaxf(m, v);
  }
  m = wave_max_f(m);
  if ((tid & 63) == 0) wred[w] = m;
  __syncthreads();
  float bm = fmaxf(fmaxf(wred[0], wred[1]), fmaxf(wred[2], wred[3]));
  __syncthreads();

  float s = 0.f;
  for (int k = tid; k < V; k += 256) s += __expf(shrow[k] - bm);
  s = wave_sum_f(s);
  if ((tid & 63) == 0) wred[w] = s;
  __syncthreads();
  float lse = bm + __logf(wred[0] + wred[1] + wred[2] + wred[3]);

  const int* lab = ctc_label + (size_t)b * L;
  float* dst = lp + ((size_t)b * TPAD + t) * ROWF;
  int nq = LANES * 4;
  for (int idx = tid; idx < nq; idx += 256) {
    int sl = idx >> 2, q = idx & 3;
    int jb = ((7 * sl) >> 1) + 1;
    int j = jb + q; if (j > L) j = L;
    int vi = lab[j - 1];
    if ((unsigned)vi >= (unsigned)V) vi = 0;
    dst[idx] = shrow[vi] - lse;
  }
  if (tid == 0) dst[nq] = shrow[0] - lse;
  for (int z = nq + 1 + tid; z < ROWF; z += 256) dst[z] = 0.f;  // pad
}

// ---------------------------------------------------------------------------
// Kernel B: Viterbi forced alignment, one 4-wave block per batch item,
// producer/consumer wave specialization:
//   wave 0 (consumer): DP over states; hot loop touches ONLY VALU + LDS
//     (ds_read ring with exact per-wave lgkmcnt(9), ds_write_b16 offrow).
//     Zero vmem in the loop -> no compiler/HW vmem waits can serialize it.
//   waves 1,2 (producers): stage 16-row lp segments global->reg->LDS into a
//     3-buffer rotation, 2 segments ahead of the consumer. All vmem latency,
//     compiler waits, and any spill traffic land here, overlapped with
//     consumer compute (~6400 cy slack per ~1400 cy of work).
//   wave 3: idles at barriers.
// Sync: one __syncthreads per 16-body window. offrow ((T-1) x 116B) in LDS;
// backtrace (wave 0) = batched speculative LDS reads.
// ---------------------------------------------------------------------------
__global__ __launch_bounds__(256, 1) void kB_viterbi(
    const float* __restrict__ lp, const int* __restrict__ ctc_label,
    float* __restrict__ ali, int B, int T, int L, int TPAD, int ROWF)
{
  extern __shared__ float smemf[];
  // LDS: buf0 @0, buf1 @15360, buf2 @30720 (16 rows x 960B each),
  //      offrow @46080, stride 116 B (58 u16 per row), (T-1) rows.
  const int N = 2 * L + 1;
  const int LANES = (N + 6) / 7;     // 58
  const unsigned STGB = 15360u;
  const unsigned OFFBASE = 3u * STGB;  // 46080

  int b = blockIdx.x;
  int tid = threadIdx.x;
  int wid = tid >> 6;
  int lane = tid & 63;
  const float* lpb = lp + (size_t)b * TPAD * ROWF;
  int NSEG = (T - 1 + 15) >> 4;

  // Stage segment k (rows 1+16k .. 16+16k) into buf[k%3].
  auto stage_seg = [&](int k) {
    const f32x4* src =
        reinterpret_cast<const f32x4*>(lpb + (size_t)(1 + 16 * k) * ROWF);
    f32x4* dst = reinterpret_cast<f32x4*>(
        reinterpret_cast<char*>(smemf) + (unsigned)(k % 3) * STGB);
#pragma unroll
    for (int kk = 0; kk < 15; ++kk) dst[kk * 64 + lane] = src[kk * 64 + lane];
  };

  if (wid != 0) {
    // ---------------- producer / idle waves ----------------
    if (wid == 1 && NSEG > 0) stage_seg(0);
    if (wid == 2 && NSEG > 1) stage_seg(1);
    __syncthreads();
    for (int sg = 0; sg < NSEG; ++sg) {
      int k = sg + 2;
      if (k < NSEG && wid == 1 + (k & 1)) stage_seg(k);
      __syncthreads();
    }
    return;
  }

  // ---------------- wave 0: consumer ----------------
  const int* lab = ctc_label + (size_t)b * L;
  int qlane = (lane < LANES) ? lane : LANES;   // 58 clamp -> blank quad
  unsigned qoff = (unsigned)(qlane * 16);

  int i0 = lane * 7;
  float a0v, a1v, a2v, a3v, a4v, a5v, a6v;
  unsigned twmask = 0;               // bit s: state i0+s is two-way
#pragma unroll
  for (int s = 0; s < 7; ++s) {
    int i = i0 + s;
    bool valid = (i < N);
    bool odd = (i & 1) != 0;
    int li = (i - 1) >> 1;
    int myl = (odd && valid) ? lab[li] : 0;
    int pl  = (odd && valid && i >= 3) ? lab[li - 1] : -1;
    if ((!odd) || (i == 1) || (myl == pl)) twmask |= (1u << s);
  }

  // t=0 init (plain global reads, drained before the LDS-ring loop).
  {
    f32x4 q00 = *reinterpret_cast<const f32x4*>(lpb + qlane * 4);
    float bl00 = lpb[LANES * 4];
    a0v = (i0 == 0) ? bl00 : NEGINF;
    a1v = NEGINF; a2v = NEGINF; a3v = NEGINF; a4v = NEGINF; a5v = NEGINF;
    a6v = NEGINF;
    if (i0 + 1 == 1) a1v = q00.x;   // only lane 0 state 1
  }
  float t6 = __shfl_up(a6v, 1, 64);
  float t5 = __shfl_up(a5v, 1, 64);
  if (lane == 0) { t6 = NEGINF; t5 = NEGINF; }

  __syncthreads();   // buf0/buf1 staged

  f32x4 rqA, rqB, rqC, rqD;
  float rblA, rblB, rblC, rblD;

#define RINGRD(SL, qaddr, baddr)                                              \
  asm volatile("ds_read_b128 %0, %1" : "=v"(rq##SL) : "v"(qaddr));            \
  asm volatile("ds_read_b32 %0, %1" : "=v"(rbl##SL) : "v"(baddr));

  unsigned wa = OFFBASE + (unsigned)(lane * 2);
  {
    // Ring warm-up: rows 0..3 of buf0 + 3 dummy writes so every body's
    // lgkmcnt(9) has >=9 ops after its pair (3 DS ops/body, 4-deep ring).
    RINGRD(A, 0u * 960u + qoff, 0u * 960u + 928u)
    RINGRD(B, 1u * 960u + qoff, 1u * 960u + 928u)
    RINGRD(C, 2u * 960u + qoff, 2u * 960u + 928u)
    RINGRD(D, 3u * 960u + qoff, 3u * 960u + 928u)
    unsigned zz = 0;
    asm volatile("ds_write_b16 %0, %1" :: "v"(wa), "v"(zz));
    asm volatile("ds_write_b16 %0, %1" :: "v"(wa), "v"(zz));
    asm volatile("ds_write_b16 %0, %1" :: "v"(wa), "v"(zz));
  }

#define STEPX(s, P0, P1, P2, OCS, ND, OD)                                     \
  {                                                                           \
    bool c01 = (P0) > (P1);                                                   \
    float m01 = c01 ? (P0) : (P1);                                            \
    bool allow3 = ((twmask >> (s)) & 1u) == 0u;                               \
    bool take3 = allow3 && !(m01 > (P2));                                     \
    float asel = take3 ? (P2) : m01;                                          \
    OD = take3 ? 2u : (c01 ? 0u : 1u);                                        \
    float lps = (((lane + (s)) & 1) ? (OCS) : blc);                           \
    ND = asel + lps;                                                          \
    bool feas = ((s) >= lo_i) && ((s) <= hi_i);                               \
    ND = feas ? ND : NEGINF;                                                  \
  }

  // One DP body. SL = ring slot (UL&3), UL = row in window, WCNT = lgkm wait.
  // CLAMP: ring target row for tail windows (no next buffer staged).
#define BODYX(SL, UL, WCNT, CLAMP)                                            \
  {                                                                           \
    const int tt = tt0 + (UL);                                                \
    int lo_i = 2 * (L - T + tt) - i0;                                         \
    int hi_i = 2 * tt - i0;                                                   \
    asm volatile("s_waitcnt lgkmcnt(" #WCNT ")");                             \
    __builtin_amdgcn_sched_barrier(0);                                        \
    float blc = rbl##SL;                                                      \
    f32x4 oc = rq##SL;                                                        \
    float n0, n1, n2, n3, n4, n5, n6;                                         \
    unsigned o0, o1, o2, o3, o4, o5, o6;                                      \
    STEPX(5, a5v, a4v, a3v, oc.z, n5, o5)                                     \
    STEPX(6, a6v, a5v, a4v, oc.w, n6, o6)                                     \
    float t6n = dpp_wave_shr1(n6);                                            \
    float t5n = dpp_wave_shr1(n5);                                            \
    STEPX(0, a0v, t6, t5, oc.x, n0, o0)                                       \
    STEPX(1, a1v, a0v, t6, oc.x, n1, o1)                                      \
    STEPX(2, a2v, a1v, a0v, oc.y, n2, o2)                                     \
    STEPX(3, a3v, a2v, a1v, oc.y, n3, o3)                                     \
    STEPX(4, a4v, a3v, a2v, oc.z, n4, o4)                                     \
    unsigned pack = o0 | (o1 << 2) | (o2 << 4) | (o3 << 6) | (o4 << 8) |      \
                    (o5 << 10) | (o6 << 12);                                  \
    if (lane < LANES)                                                         \
      asm volatile("ds_write_b16 %0, %1" :: "v"(wa), "v"(pack));              \
    wa += 116;                                                                \
    {                                                                         \
      unsigned rbase;                                                         \
      if (CLAMP) {                                                            \
        rbase = bufc + (((UL) < 12) ? ((UL) + 4) : 15) * 960u;                \
      } else {                                                                \
        rbase = ((UL) < 12) ? (bufc + ((UL) + 4) * 960u)                      \
                            : (bufn + ((UL) - 12) * 960u);                    \
      }                                                                       \
      RINGRD(SL, rbase + qoff, rbase + 928u)                                  \
    }                                                                         \
    a0v = n0; a1v = n1; a2v = n2; a3v = n3; a4v = n4; a5v = n5; a6v = n6;     \
    t6 = (lane == 0) ? NEGINF : t6n;                                          \
    t5 = (lane == 0) ? NEGINF : t5n;                                          \
  }

  for (int sg = 0; sg < NSEG; ++sg) {
    int tt0 = 1 + 16 * sg;
    unsigned bufc = (unsigned)(sg % 3) * STGB;
    unsigned bufn = (sg + 1 < NSEG) ? (unsigned)((sg + 1) % 3) * STGB : bufc;
    int rem = T - tt0;   // bodies this window (16 except last)
    if (rem >= 16) {
      BODYX(A, 0, 9, 0)  BODYX(B, 1, 9, 0)  BODYX(C, 2, 9, 0)
      BODYX(D, 3, 9, 0)  BODYX(A, 4, 9, 0)  BODYX(B, 5, 9, 0)
      BODYX(C, 6, 9, 0)  BODYX(D, 7, 9, 0)  BODYX(A, 8, 9, 0)
      BODYX(B, 9, 9, 0)  BODYX(C, 10, 9, 0) BODYX(D, 11, 9, 0)
      BODYX(A, 12, 9, 0) BODYX(B, 13, 9, 0) BODYX(C, 14, 9, 0)
      BODYX(D, 15, 9, 0)
    } else {
      if (rem > 0)  { BODYX(A, 0, 0, 1) }
      if (rem > 1)  { BODYX(B, 1, 0, 1) }
      if (rem > 2)  { BODYX(C, 2, 0, 1) }
      if (rem > 3)  { BODYX(D, 3, 0, 1) }
      if (rem > 4)  { BODYX(A, 4, 0, 1) }
      if (rem > 5)  { BODYX(B, 5, 0, 1) }
      if (rem > 6)  { BODYX(C, 6, 0, 1) }
      if (rem > 7)  { BODYX(D, 7, 0, 1) }
      if (rem > 8)  { BODYX(A, 8, 0, 1) }
      if (rem > 9)  { BODYX(B, 9, 0, 1) }
      if (rem > 10) { BODYX(C, 10, 0, 1) }
      if (rem > 11) { BODYX(D, 11, 0, 1) }
      if (rem > 12) { BODYX(A, 12, 0, 1) }
      if (rem > 13) { BODYX(B, 13, 0, 1) }
      if (rem > 14) { BODYX(C, 14, 0, 1) }
    }
    __syncthreads();
  }
#undef BODYX
#undef STEPX
#undef RINGRD

  // Drain before compiler-visible LDS reads (backtrace).
  asm volatile("s_waitcnt vmcnt(0) lgkmcnt(0)" ::: "memory");
  __builtin_amdgcn_sched_barrier(0);

  // Final-state values (state i -> lane i/7, slot i%7).
  int iN1 = N - 1, iN2 = N - 2;
  auto pick = [&](int sIdx) {
    float r = a0v;
    r = (sIdx == 1) ? a1v : r;
    r = (sIdx == 2) ? a2v : r;
    r = (sIdx == 3) ? a3v : r;
    r = (sIdx == 4) ? a4v : r;
    r = (sIdx == 5) ? a5v : r;
    r = (sIdx == 6) ? a6v : r;
    return r;
  };
  float vlast = __shfl(pick(iN1 % 7), iN1 / 7, 64);
  float vprev = __shfl(pick(iN2 % 7), iN2 / 7, 64);
  bool use_last = vlast > vprev;
  int pre = use_last ? iN1 : iN2;

  float al[4] = {0.f, 0.f, 0.f, 0.f};
  {
    int lbl = L - 1; int rr = lbl >> 6, ln = lbl & 63;
#pragma unroll
    for (int r = 0; r < 4; ++r)
      if (!use_last && rr == r && lane == ln) al[r] = (float)T;
  }

  // Backtrace from LDS offrow (rows of 58 u16; entry g of row t-1).
  const unsigned short* offrow =
      (const unsigned short*)((char*)smemf + OFFBASE);
  int t = T - 1;
  int g = pre / 7, mm = pre - g * 7;
  while (t >= 1) {
    int K = (t < 7) ? t : 7;
    int pcur = g * 7 + mm;
    int gmax = g;
    unsigned short w0v = offrow[(size_t)(t - 1) * 58 + g];
    unsigned short cw[7][3];
    int gmn[7];
#pragma unroll
    for (int j = 1; j < 7; ++j) {
      if (j < K) {
        int lo = pcur - 2 * j; if (lo < 0) lo = 0;
        int gm = lo / 7;
        gmn[j] = gm;
#pragma unroll
        for (int r = 0; r < 3; ++r) {
          int gg = gm + r; if (gg > gmax) gg = gmax;
          cw[j][r] = offrow[(size_t)(t - 1 - j) * 58 + gg];
        }
      }
    }
#pragma unroll
    for (int j = 0; j < 7; ++j) {
      if (j < K) {
        unsigned w;
        if (j == 0) {
          w = w0v;
        } else {
          int gi = g - gmn[j];
          unsigned wva = cw[j][0], wvb = cw[j][1], wvc = cw[j][2];
          w = (gi == 0) ? wva : ((gi == 1) ? wvb : wvc);
        }
        unsigned off = (w >> (2 * mm)) & 3u;
        mm -= (int)off;
        bool bor = mm < 0;
        g = bor ? (g - 1) : g;
        mm = bor ? (mm + 7) : mm;
        int cur = g * 7 + mm;
        if (cur & 1) {
          int lbl = cur >> 1;
          int rr = lbl >> 6, ln = lbl & 63;
#pragma unroll
          for (int r = 0; r < 4; ++r)
            if (rr == r && lane == ln) al[r] = (float)(t - j);
        }
      }
    }
    t -= K;
  }

#pragma unroll
  for (int r = 0; r < 4; ++r) {
    int l = lane + 64 * r;
    if (l < L) ali[(size_t)b * L + l] = al[r];
  }
}

// ---------------------------------------------------------------------------
// Kernel C: one wave per (b,layer,o<L) row: dot(ali_out_row, pos) - ali,
// masked, squared; 4 rows/block -> per-block partial sum.
// ---------------------------------------------------------------------------
__global__ __launch_bounds__(256) void kC_rows(
    const float* __restrict__ ali_out, const float* __restrict__ ali,
    const int* __restrict__ ali_beg, float* __restrict__ partials,
    int B, int layers, int L, int T)
{
  __shared__ float ps[4];
  int wid = threadIdx.x >> 6, lane = threadIdx.x & 63;
  int row = blockIdx.x * 4 + wid;
  int nrows = B * layers * L;
  float val = 0.f;
  if (row < nrows) {
    int o = row % L;
    int bl = row / L;
    int layer = bl % layers;
    int b = bl / layers;
    const float* x = ali_out + ((size_t)(b * layers + layer) * (L + 1) + o) * T;
    float s = 0.f;
    if ((T & 3) == 0) {
      int nf4 = T >> 2;
      for (int k = lane; k < nf4; k += 64) {
        float4 v = reinterpret_cast<const float4*>(x)[k];
        float base = (float)(4 * k);
        s += v.x * (base + 1.f) + v.y * (base + 2.f) +
             v.z * (base + 3.f) + v.w * (base + 4.f);
      }
    } else {
      for (int k = lane; k < T; k += 64) s += x[k] * (float)(k + 1);
    }
    s = wave_sum_f(s);
    int cnt = 0;
    for (int l = lane; l < L; l += 64)
      cnt += (ali_beg[(size_t)b * L + l] != -1) ? 1 : 0;
    cnt = wave_sum_i(cnt);
    if (lane == 0) {
      float lat = (o >= cnt) ? 0.f : (s - ali[(size_t)b * L + o]);
      val = lat * lat;
    }
  }
  if (lane == 0) ps[wid] = val;
  __syncthreads();
  if (threadIdx.x == 0) partials[blockIdx.x] = ps[0] + ps[1] + ps[2] + ps[3];
}

// ---------------------------------------------------------------------------
// Kernel D: reduce partials, compute total = layers * sum(ylen), write scalar.
// ---------------------------------------------------------------------------
__global__ __launch_bounds__(256) void kD_final(
    const float* __restrict__ partials, int nparts,
    const int* __restrict__ ali_beg, int BL, int layers, int T,
    float* __restrict__ out)
{
  __shared__ float wred[4];
  __shared__ int wcnt[4];
  int tid = threadIdx.x, w = tid >> 6;
  float s = 0.f;
  for (int k = tid; k < nparts; k += 256) s += partials[k];
  s = wave_sum_f(s);
  int c = 0;
  for (int k = tid; k < BL; k += 256) c += (ali_beg[k] != -1) ? 1 : 0;
  c = wave_sum_i(c);
  if ((tid & 63) == 0) { wred[w] = s; wcnt[w] = c; }
  __syncthreads();
  if (tid == 0) {
    float ss = wred[0] + wred[1] + wred[2] + wred[3];
    float total = (float)(wcnt[0] + wcnt[1] + wcnt[2] + wcnt[3]) * (float)layers;
    out[0] = ss / total / (float)T;
  }
}

extern "C" void kernel_launch(void* const* d_in, const int* in_sizes, int n_in,
                              void* d_out, int out_size, void* d_ws, size_t ws_size,
                              hipStream_t stream)
{
  const float* ali_out   = (const float*)d_in[0];
  const int*   ali_beg   = (const int*)d_in[1];
  // d_in[2] ali_end, d_in[3] enc_mask, d_in[6] ctc_len: unused by reference math
  const float* ctc_out   = (const float*)d_in[4];
  const int*   ctc_label = (const int*)d_in[5];

  int B = in_sizes[6];
  int L = in_sizes[1] / B;
  int T = in_sizes[3] / B;
  int V = (int)((long long)in_sizes[4] / ((long long)B * T));
  int layers = (int)((long long)in_sizes[0] / ((long long)B * (L + 1) * T));

  int N = 2 * L + 1;
  int LANES = (N + 6) / 7;           // 58
  int ROWF = LANES * 4 + 8;          // 240 floats (960 B)
  int TPAD = T + 64;                 // staging over-read pad

  // workspace layout
  float* lp = (float*)d_ws;                              // B*TPAD*ROWF floats
  float* ali = lp + (size_t)B * TPAD * ROWF;             // B*L
  float* partials = ali + (size_t)B * L;                 // gridC
  int nrows = B * layers * L;
  int gridC = (nrows + 3) / 4;

  // A: logsumexp + gather into packed rows
  size_t shA = (size_t)V * sizeof(float);
  hipLaunchKernelGGL(kA_lse_gather, dim3(B * T), dim3(256), shA, stream,
                     ctc_out, ctc_label, lp, B, T, V, L, LANES, TPAD, ROWF);

  // B: Viterbi forward + backtrace (4 waves per batch item: 1 consumer,
  // 2 producers, 1 idle). LDS: 3 staging buffers + offrow (T-1)*116 B.
  size_t shB = (size_t)3 * 15360 + (size_t)(T - 1) * 116;
  hipFuncSetAttribute(reinterpret_cast<const void*>(kB_viterbi),
                      hipFuncAttributeMaxDynamicSharedMemorySize, (int)shB);
  hipLaunchKernelGGL(kB_viterbi, dim3(B), dim3(256), shB, stream,
                     lp, ctc_label, ali, B, T, L, TPAD, ROWF);

  // C: expected-position rows + squared residual partials
  hipLaunchKernelGGL(kC_rows, dim3(gridC), dim3(256), 0, stream,
                     ali_out, ali, ali_beg, partials, B, layers, L, T);

  // D: finalize scalar
  hipLaunchKernelGGL(kD_final, dim3(1), dim3(256), 0, stream,
                     partials, gridC, ali_beg, B * L, layers, T, (float*)d_out);
}

// Round 11
// 533.433 us; speedup vs baseline: 1.0609x; 1.0609x over previous
//
#include <hip/hip_runtime.h>
#include <hip/hip_bf16.h>
#include <math.h>

#define NEGINF (-INFINITY)

typedef float f32x4 __attribute__((ext_vector_type(4)));

__device__ __forceinline__ float wave_max_f(float m) {
#pragma unroll
  for (int d = 32; d > 0; d >>= 1) m = fmaxf(m, __shfl_xor(m, d, 64));
  return m;
}
__device__ __forceinline__ float wave_sum_f(float s) {
#pragma unroll
  for (int d = 32; d > 0; d >>= 1) s += __shfl_xor(s, d, 64);
  return s;
}
__device__ __forceinline__ int wave_sum_i(int s) {
#pragma unroll
  for (int d = 32; d > 0; d >>= 1) s += __shfl_xor(s, d, 64);
  return s;
}

// Whole-wave shift-right-by-1 via DPP (pure VALU). Lane l gets lane l-1's
// value; lane 0 gets 0 (caller overrides).
__device__ __forceinline__ float dpp_wave_shr1(float x) {
  int r = __builtin_amdgcn_mov_dpp(__float_as_int(x), 0x138, 0xf, 0xf, true);
  return __int_as_float(r);
}

// ---------------------------------------------------------------------------
// Kernel A: per (b,t) row of ctc_out[V]: logsumexp, then gather into packed
// row layout (stride ROWF=LANES*4+8 floats = 960 B):
//   row[0 .. LANES*4)  = label lps, quad s -> labels jbase(s)..+3 (clamped)
//   row[LANES*4]       = blank lp   (i.e. lane 58's quad .x = blank)
//   row[LANES*4+1 ..]  = zero pad
// ---------------------------------------------------------------------------
__global__ __launch_bounds__(256) void kA_lse_gather(
    const float* __restrict__ ctc_out, const int* __restrict__ ctc_label,
    float* __restrict__ lp, int B, int T, int V, int L, int LANES,
    int TPAD, int ROWF)
{
  extern __shared__ float shrow[];  // V floats
  __shared__ float wred[4];
  int row = blockIdx.x;             // b*T + t
  int b = row / T;
  int t = row - b * T;
  int tid = threadIdx.x;
  int w = tid >> 6;
  const float* x = ctc_out + (size_t)row * V;

  float m = NEGINF;
  int nf4 = V >> 2;
  for (int k = tid; k < nf4; k += 256) {
    float4 v = reinterpret_cast<const float4*>(x)[k];
    reinterpret_cast<float4*>(shrow)[k] = v;
    m = fmaxf(m, fmaxf(fmaxf(v.x, v.y), fmaxf(v.z, v.w)));
  }
  for (int k = (nf4 << 2) + tid; k < V; k += 256) {
    float v = x[k]; shrow[k] = v; m = fmaxf(m, v);
  }
  m = wave_max_f(m);
  if ((tid & 63) == 0) wred[w] = m;
  __syncthreads();
  float bm = fmaxf(fmaxf(wred[0], wred[1]), fmaxf(wred[2], wred[3]));
  __syncthreads();

  float s = 0.f;
  for (int k = tid; k < V; k += 256) s += __expf(shrow[k] - bm);
  s = wave_sum_f(s);
  if ((tid & 63) == 0) wred[w] = s;
  __syncthreads();
  float lse = bm + __logf(wred[0] + wred[1] + wred[2] + wred[3]);

  const int* lab = ctc_label + (size_t)b * L;
  float* dst = lp + ((size_t)b * TPAD + t) * ROWF;
  int nq = LANES * 4;
  for (int idx = tid; idx < nq; idx += 256) {
    int sl = idx >> 2, q = idx & 3;
    int jb = ((7 * sl) >> 1) + 1;
    int j = jb + q; if (j > L) j = L;
    int vi = lab[j - 1];
    if ((unsigned)vi >= (unsigned)V) vi = 0;
    dst[idx] = shrow[vi] - lse;
  }
  if (tid == 0) dst[nq] = shrow[0] - lse;
  for (int z = nq + 1 + tid; z < ROWF; z += 256) dst[z] = 0.f;  // pad
}

// ---------------------------------------------------------------------------
// Kernel B: Viterbi forced alignment, one wave per batch item.
// Same structure as R8/R9 (8-slot asm global dwordx4 ring, vmcnt(7),
// readlane blank, DPP shift, band feasibility, LDS offrow) but the hot loop
// is ROLLED to a single 8-body block (~6-9 KB) so it fits L1 I-cache.
// Theory: the persistent ~900cy/body across R2-R10 was instruction-fetch
// bound (dual fast/slow 16-body unrolls = 25-38KB of hot code); memory
// restructuring never changed it because the loop was refetching code.
// ---------------------------------------------------------------------------
__global__ __launch_bounds__(64, 1) void kB_viterbi(
    const float* __restrict__ lp, const int* __restrict__ ctc_label,
    float* __restrict__ ali, int B, int T, int L, int TPAD, int ROWF)
{
  extern __shared__ float smemf[];   // offrow only: (T-1)*128 B
  const int N = 2 * L + 1;
  const int LANES = (N + 6) / 7;     // 58

  int b = blockIdx.x;
  int lane = threadIdx.x;
  const float* lpb = lp + (size_t)b * TPAD * ROWF;
  const int* lab = ctc_label + (size_t)b * L;
  int qlane = (lane < LANES) ? lane : LANES;  // lanes 58..63 -> blank quad

  int i0 = lane * 7;
  float a0v, a1v, a2v, a3v, a4v, a5v, a6v;
  unsigned twmask = 0;               // bit s: state i0+s is two-way
#pragma unroll
  for (int s = 0; s < 7; ++s) {
    int i = i0 + s;
    bool valid = (i < N);
    bool odd = (i & 1) != 0;
    int li = (i - 1) >> 1;
    int myl = (odd && valid) ? lab[li] : 0;
    int pl  = (odd && valid && i >= 3) ? lab[li - 1] : -1;
    if ((!odd) || (i == 1) || (myl == pl)) twmask |= (1u << s);
  }

  // t=0 init (plain compiler loads; drained before the asm ring starts).
  {
    f32x4 q00 = *reinterpret_cast<const f32x4*>(lpb + qlane * 4);
    float bl00 = lpb[LANES * 4];
    a0v = (i0 == 0) ? bl00 : NEGINF;
    a1v = NEGINF; a2v = NEGINF; a3v = NEGINF; a4v = NEGINF; a5v = NEGINF;
    a6v = NEGINF;
    if (i0 + 1 == 1) a1v = q00.x;   // only lane 0 state 1
  }

  f32x4 rq0, rq1, rq2, rq3, rq4, rq5, rq6, rq7;
  unsigned short* offrow_w = (unsigned short*)smemf;

  // Ensure no compiler vmem is outstanding before our counted ring starts.
  asm volatile("s_waitcnt vmcnt(0) lgkmcnt(0)");
  __builtin_amdgcn_sched_barrier(0);

  unsigned long long base64 = (unsigned long long)lpb;
  unsigned voff = (unsigned)(qlane * 16) + 960u;   // row 1

#define LOADQ(SL)                                                             \
  asm volatile("global_load_dwordx4 %0, %1, %2"                               \
               : "=v"(rq##SL) : "v"(voff), "s"(base64));                      \
  voff += 960u;

  // Prologue: rows 1..8 -> slots 1..7,0 (slot = row & 7). voff ends at row 9.
  LOADQ(1) LOADQ(2) LOADQ(3) LOADQ(4) LOADQ(5) LOADQ(6) LOADQ(7) LOADQ(0)

#define STEPU(s, P0, P1, P2, OCS, ND, OD)                                     \
  {                                                                           \
    bool c01 = (P0) > (P1);                                                   \
    float m01 = c01 ? (P0) : (P1);                                            \
    bool allow3 = ((twmask >> (s)) & 1u) == 0u;                               \
    bool take3 = allow3 && !(m01 > (P2));                                     \
    float asel = take3 ? (P2) : m01;                                          \
    OD = take3 ? 2u : (c01 ? 0u : 1u);                                        \
    float lps = (((lane + (s)) & 1) ? (OCS) : blc);                           \
    ND = asel + lps;                                                          \
    bool feas = ((s) >= lo_i) && ((s) <= hi_i);                               \
    ND = feas ? ND : NEGINF;                                                  \
  }

  // One DP body. SL = ring slot (== tt&7 since tt0 === 1 mod 8).
#define BODYC(SL, K)                                                          \
  {                                                                           \
    const int tt = tt0 + (K);                                                 \
    int lo_i = 2 * (L - T + tt) - i0;   /* feasible: lo_i <= s */             \
    int hi_i = 2 * tt - i0;             /* feasible: s <= hi_i */             \
    asm volatile("s_waitcnt vmcnt(7)");                                       \
    __builtin_amdgcn_sched_barrier(0);                                        \
    float blc = __int_as_float(                                               \
        __builtin_amdgcn_readlane(__float_as_int(rq##SL.x), 58));             \
    float n0, n1, n2, n3, n4, n5, n6;                                         \
    unsigned o0, o1, o2, o3, o4, o5, o6;                                      \
    STEPU(5, a5v, a4v, a3v, rq##SL.z, n5, o5)                                 \
    STEPU(6, a6v, a5v, a4v, rq##SL.w, n6, o6)                                 \
    float t6n = dpp_wave_shr1(n6);                                            \
    float t5n = dpp_wave_shr1(n5);                                            \
    STEPU(0, a0v, t6, t5, rq##SL.x, n0, o0)                                   \
    STEPU(1, a1v, a0v, t6, rq##SL.x, n1, o1)                                  \
    STEPU(2, a2v, a1v, a0v, rq##SL.y, n2, o2)                                 \
    STEPU(3, a3v, a2v, a1v, rq##SL.y, n3, o3)                                 \
    STEPU(4, a4v, a3v, a2v, rq##SL.z, n4, o4)                                 \
    unsigned pack = o0 | (o1 << 2) | (o2 << 4) | (o3 << 6) | (o4 << 8) |      \
                    (o5 << 10) | (o6 << 12);                                  \
    offrow_w[(size_t)(tt - 1) * 64 + lane] = (unsigned short)pack;            \
    LOADQ(SL)                                                                 \
    a0v = n0; a1v = n1; a2v = n2; a3v = n3; a4v = n4; a5v = n5; a6v = n6;     \
    t6 = (lane == 0) ? NEGINF : t6n;                                          \
    t5 = (lane == 0) ? NEGINF : t5n;                                          \
  }

  // Initial shifted values from t=0 state (outside hot loop).
  float t6 = __shfl_up(a6v, 1, 64);
  float t5 = __shfl_up(a5v, 1, 64);
  if (lane == 0) { t6 = NEGINF; t5 = NEGINF; }

  // MAIN LOOP: single rolled 8-body block (fits I-cache). Feasibility is
  // always computed (no fast/slow code duplication).
  int tt0 = 1;
  for (; tt0 + 8 <= T; tt0 += 8) {
    BODYC(1, 0) BODYC(2, 1) BODYC(3, 2) BODYC(4, 3)
    BODYC(5, 4) BODYC(6, 5) BODYC(7, 6) BODYC(0, 7)
  }
  {
    int rem = T - tt0;   // 0..7 remaining bodies (cold tail, runs once)
    if (rem > 0) { BODYC(1, 0) }
    if (rem > 1) { BODYC(2, 1) }
    if (rem > 2) { BODYC(3, 2) }
    if (rem > 3) { BODYC(4, 3) }
    if (rem > 4) { BODYC(5, 4) }
    if (rem > 5) { BODYC(6, 5) }
    if (rem > 6) { BODYC(7, 6) }
  }
#undef BODYC
#undef STEPU
#undef LOADQ

  // Drain the ring; keep destinations live until after the drain.
  asm volatile("s_waitcnt vmcnt(0) lgkmcnt(0)" ::: "memory");
  __builtin_amdgcn_sched_barrier(0);
  asm volatile("" :: "v"(rq0), "v"(rq1), "v"(rq2), "v"(rq3));
  asm volatile("" :: "v"(rq4), "v"(rq5), "v"(rq6), "v"(rq7));

  // Final-state values (state i -> lane i/7, slot i%7).
  int iN1 = N - 1, iN2 = N - 2;
  auto pick = [&](int sIdx) {
    float r = a0v;
    r = (sIdx == 1) ? a1v : r;
    r = (sIdx == 2) ? a2v : r;
    r = (sIdx == 3) ? a3v : r;
    r = (sIdx == 4) ? a4v : r;
    r = (sIdx == 5) ? a5v : r;
    r = (sIdx == 6) ? a6v : r;
    return r;
  };
  float vlast = __shfl(pick(iN1 % 7), iN1 / 7, 64);
  float vprev = __shfl(pick(iN2 % 7), iN2 / 7, 64);
  bool use_last = vlast > vprev;
  int pre = use_last ? iN1 : iN2;

  float al[4] = {0.f, 0.f, 0.f, 0.f};
  {
    int lbl = L - 1; int rr = lbl >> 6, ln = lbl & 63;
#pragma unroll
    for (int r = 0; r < 4; ++r)
      if (!use_last && rr == r && lane == ln) al[r] = (float)T;
  }

  // Backtrace from LDS offrow (rows of 64 u16; entry g of row t-1).
  const unsigned short* offrow = (const unsigned short*)smemf;
  int t = T - 1;
  int g = pre / 7, mm = pre - g * 7;
  while (t >= 1) {
    int K = (t < 7) ? t : 7;
    int pcur = g * 7 + mm;
    int gmax = g;
    unsigned short w0v = offrow[(size_t)(t - 1) * 64 + g];
    unsigned short cw[7][3];
    int gmn[7];
#pragma unroll
    for (int j = 1; j < 7; ++j) {
      if (j < K) {
        int lo = pcur - 2 * j; if (lo < 0) lo = 0;
        int gm = lo / 7;
        gmn[j] = gm;
#pragma unroll
        for (int r = 0; r < 3; ++r) {
          int gg = gm + r; if (gg > gmax) gg = gmax;
          cw[j][r] = offrow[(size_t)(t - 1 - j) * 64 + gg];
        }
      }
    }
#pragma unroll
    for (int j = 0; j < 7; ++j) {
      if (j < K) {
        unsigned w;
        if (j == 0) {
          w = w0v;
        } else {
          int gi = g - gmn[j];
          unsigned wva = cw[j][0], wvb = cw[j][1], wvc = cw[j][2];
          w = (gi == 0) ? wva : ((gi == 1) ? wvb : wvc);
        }
        unsigned off = (w >> (2 * mm)) & 3u;
        mm -= (int)off;
        bool bor = mm < 0;
        g = bor ? (g - 1) : g;
        mm = bor ? (mm + 7) : mm;
        int cur = g * 7 + mm;
        if (cur & 1) {
          int lbl = cur >> 1;
          int rr = lbl >> 6, ln = lbl & 63;
#pragma unroll
          for (int r = 0; r < 4; ++r)
            if (rr == r && lane == ln) al[r] = (float)(t - j);
        }
      }
    }
    t -= K;
  }

#pragma unroll
  for (int r = 0; r < 4; ++r) {
    int l = lane + 64 * r;
    if (l < L) ali[(size_t)b * L + l] = al[r];
  }
}

// ---------------------------------------------------------------------------
// Kernel C: one wave per (b,layer,o<L) row: dot(ali_out_row, pos) - ali,
// masked, squared; 4 rows/block -> per-block partial sum.
// ---------------------------------------------------------------------------
__global__ __launch_bounds__(256) void kC_rows(
    const float* __restrict__ ali_out, const float* __restrict__ ali,
    const int* __restrict__ ali_beg, float* __restrict__ partials,
    int B, int layers, int L, int T)
{
  __shared__ float ps[4];
  int wid = threadIdx.x >> 6, lane = threadIdx.x & 63;
  int row = blockIdx.x * 4 + wid;
  int nrows = B * layers * L;
  float val = 0.f;
  if (row < nrows) {
    int o = row % L;
    int bl = row / L;
    int layer = bl % layers;
    int b = bl / layers;
    const float* x = ali_out + ((size_t)(b * layers + layer) * (L + 1) + o) * T;
    float s = 0.f;
    if ((T & 3) == 0) {
      int nf4 = T >> 2;
      for (int k = lane; k < nf4; k += 64) {
        float4 v = reinterpret_cast<const float4*>(x)[k];
        float base = (float)(4 * k);
        s += v.x * (base + 1.f) + v.y * (base + 2.f) +
             v.z * (base + 3.f) + v.w * (base + 4.f);
      }
    } else {
      for (int k = lane; k < T; k += 64) s += x[k] * (float)(k + 1);
    }
    s = wave_sum_f(s);
    int cnt = 0;
    for (int l = lane; l < L; l += 64)
      cnt += (ali_beg[(size_t)b * L + l] != -1) ? 1 : 0;
    cnt = wave_sum_i(cnt);
    if (lane == 0) {
      float lat = (o >= cnt) ? 0.f : (s - ali[(size_t)b * L + o]);
      val = lat * lat;
    }
  }
  if (lane == 0) ps[wid] = val;
  __syncthreads();
  if (threadIdx.x == 0) partials[blockIdx.x] = ps[0] + ps[1] + ps[2] + ps[3];
}

// ---------------------------------------------------------------------------
// Kernel D: reduce partials, compute total = layers * sum(ylen), write scalar.
// ---------------------------------------------------------------------------
__global__ __launch_bounds__(256) void kD_final(
    const float* __restrict__ partials, int nparts,
    const int* __restrict__ ali_beg, int BL, int layers, int T,
    float* __restrict__ out)
{
  __shared__ float wred[4];
  __shared__ int wcnt[4];
  int tid = threadIdx.x, w = tid >> 6;
  float s = 0.f;
  for (int k = tid; k < nparts; k += 256) s += partials[k];
  s = wave_sum_f(s);
  int c = 0;
  for (int k = tid; k < BL; k += 256) c += (ali_beg[k] != -1) ? 1 : 0;
  c = wave_sum_i(c);
  if ((tid & 63) == 0) { wred[w] = s; wcnt[w] = c; }
  __syncthreads();
  if (tid == 0) {
    float ss = wred[0] + wred[1] + wred[2] + wred[3];
    float total = (float)(wcnt[0] + wcnt[1] + wcnt[2] + wcnt[3]) * (float)layers;
    out[0] = ss / total / (float)T;
  }
}

extern "C" void kernel_launch(void* const* d_in, const int* in_sizes, int n_in,
                              void* d_out, int out_size, void* d_ws, size_t ws_size,
                              hipStream_t stream)
{
  const float* ali_out   = (const float*)d_in[0];
  const int*   ali_beg   = (const int*)d_in[1];
  // d_in[2] ali_end, d_in[3] enc_mask, d_in[6] ctc_len: unused by reference math
  const float* ctc_out   = (const float*)d_in[4];
  const int*   ctc_label = (const int*)d_in[5];

  int B = in_sizes[6];
  int L = in_sizes[1] / B;
  int T = in_sizes[3] / B;
  int V = (int)((long long)in_sizes[4] / ((long long)B * T));
  int layers = (int)((long long)in_sizes[0] / ((long long)B * (L + 1) * T));

  int N = 2 * L + 1;
  int LANES = (N + 6) / 7;           // 58
  int ROWF = LANES * 4 + 8;          // 240 floats (960 B)
  int TPAD = T + 64;                 // ring over-read pad

  // workspace layout
  float* lp = (float*)d_ws;                              // B*TPAD*ROWF floats
  float* ali = lp + (size_t)B * TPAD * ROWF;             // B*L
  float* partials = ali + (size_t)B * L;                 // gridC
  int nrows = B * layers * L;
  int gridC = (nrows + 3) / 4;

  // A: logsumexp + gather into packed rows
  size_t shA = (size_t)V * sizeof(float);
  hipLaunchKernelGGL(kA_lse_gather, dim3(B * T), dim3(256), shA, stream,
                     ctc_out, ctc_label, lp, B, T, V, L, LANES, TPAD, ROWF);

  // B: Viterbi forward + backtrace (one wave per batch item)
  // LDS: offrow only, (T-1)*128 B
  size_t shB = (size_t)(T - 1) * 128;
  hipFuncSetAttribute(reinterpret_cast<const void*>(kB_viterbi),
                      hipFuncAttributeMaxDynamicSharedMemorySize, (int)shB);
  hipLaunchKernelGGL(kB_viterbi, dim3(B), dim3(64), shB, stream,
                     lp, ctc_label, ali, B, T, L, TPAD, ROWF);

  // C: expected-position rows + squared residual partials
  hipLaunchKernelGGL(kC_rows, dim3(gridC), dim3(256), 0, stream,
                     ali_out, ali, ali_beg, partials, B, layers, L, T);

  // D: finalize scalar
  hipLaunchKernelGGL(kD_final, dim3(1), dim3(256), 0, stream,
                     partials, gridC, ali_beg, B * L, layers, T, (float*)d_out);
}